// Round 1
// baseline (1945.679 us; speedup 1.0000x reference)
//
#include <hip/hip_runtime.h>
#include <hip/hip_bf16.h>

#define IN_DIM 256
#define OUT_DIM 64
#define KC 32          // k-chunk staged in LDS
#define GB 256         // gemm block threads == rows per block

// ---------------- GEMM: z = h @ W ; el = z@a1 ; er = z@a2 ----------------
__global__ __launch_bounds__(GB, 4) void k_gemm(const float* __restrict__ h,
                                                const float* __restrict__ W,
                                                const float* __restrict__ a,
                                                float* __restrict__ z,
                                                float* __restrict__ el,
                                                float* __restrict__ er, int n) {
  __shared__ float Hl[GB][KC + 1];  // +1 pad: bank (t+k)%32, conflict-free
  const int t = threadIdx.x;
  const int row = blockIdx.x * GB + t;

  float acc[OUT_DIM];
#pragma unroll
  for (int c = 0; c < OUT_DIM; ++c) acc[c] = 0.f;

  for (int k0 = 0; k0 < IN_DIM; k0 += KC) {
    __syncthreads();
    // stage h[block rows][k0:k0+KC] -> LDS. 2048 float4, 8 per thread.
#pragma unroll
    for (int i = 0; i < 8; ++i) {
      int f = i * GB + t;
      int r = f >> 3, j = f & 7;
      int grow = blockIdx.x * GB + r;
      float4 v = make_float4(0.f, 0.f, 0.f, 0.f);
      if (grow < n)
        v = *(const float4*)(h + (size_t)grow * IN_DIM + k0 + j * 4);
      Hl[r][4 * j + 0] = v.x;
      Hl[r][4 * j + 1] = v.y;
      Hl[r][4 * j + 2] = v.z;
      Hl[r][4 * j + 3] = v.w;
    }
    __syncthreads();
#pragma unroll 4
    for (int k = 0; k < KC; ++k) {
      float hv = Hl[t][k];
      const float4* Wr = (const float4*)(W + (size_t)(k0 + k) * OUT_DIM);
#pragma unroll
      for (int c4 = 0; c4 < OUT_DIM / 4; ++c4) {
        float4 w = Wr[c4];
        acc[c4 * 4 + 0] += hv * w.x;
        acc[c4 * 4 + 1] += hv * w.y;
        acc[c4 * 4 + 2] += hv * w.z;
        acc[c4 * 4 + 3] += hv * w.w;
      }
    }
  }

  if (row < n) {
    float4* zr = (float4*)(z + (size_t)row * OUT_DIM);
#pragma unroll
    for (int c4 = 0; c4 < OUT_DIM / 4; ++c4)
      zr[c4] = make_float4(acc[c4 * 4 + 0], acc[c4 * 4 + 1], acc[c4 * 4 + 2],
                           acc[c4 * 4 + 3]);
    float e1 = 0.f, e2 = 0.f;
#pragma unroll
    for (int c = 0; c < OUT_DIM; ++c) {
      e1 += acc[c] * a[c];
      e2 += acc[c] * a[OUT_DIM + c];
    }
    el[row] = e1;
    er[row] = e2;
  }
}

// ------------- edge pass: ex = exp(leaky(el[s]+er[d])); s[d]+=ex -------------
__global__ __launch_bounds__(256) void k_edge(const int* __restrict__ src,
                                              const int* __restrict__ dst,
                                              const float* __restrict__ el,
                                              const float* __restrict__ er,
                                              float* __restrict__ exw,
                                              float* __restrict__ ssum, int E) {
  int i = blockIdx.x * 256 + threadIdx.x;
  if (i >= E) return;
  int s = src[i], d = dst[i];
  float x = el[s] + er[d];
  x = x > 0.f ? x : 0.01f * x;
  float ex = __expf(x);
  exw[i] = ex;
  atomicAdd(ssum + d, ex);
}

// ------------- invert segment sums in place: s[i] = 1/s[i] -------------
__global__ __launch_bounds__(256) void k_inv(float* __restrict__ ssum, int n) {
  int i = blockIdx.x * 256 + threadIdx.x;
  if (i < n) ssum[i] = 1.f / ssum[i];
}

// ------- scatter: out[d][:] += (ex[e]*inv_s[d]) * z[s][:], 16 lanes/edge -------
__global__ __launch_bounds__(256) void k_scatter(const int* __restrict__ src,
                                                 const int* __restrict__ dst,
                                                 const float* __restrict__ exw,
                                                 const float* __restrict__ inv_s,
                                                 const float* __restrict__ z,
                                                 float* __restrict__ out, int E) {
  int gid = blockIdx.x * 256 + threadIdx.x;
  int e = gid >> 4;
  if (e >= E) return;
  int c = (gid & 15) * 4;
  int s = src[e], d = dst[e];
  float alpha = exw[e] * inv_s[d];
  float4 v = *(const float4*)(z + (size_t)s * OUT_DIM + c);
  float* op = out + (size_t)d * OUT_DIM + c;
  atomicAdd(op + 0, alpha * v.x);
  atomicAdd(op + 1, alpha * v.y);
  atomicAdd(op + 2, alpha * v.z);
  atomicAdd(op + 3, alpha * v.w);
}

// ------------- elu in place on d_out -------------
__global__ __launch_bounds__(256) void k_elu(float* __restrict__ out, size_t n4) {
  size_t i = (size_t)blockIdx.x * 256 + threadIdx.x;
  if (i >= n4) return;
  float4 x = ((float4*)out)[i];
  x.x = x.x > 0.f ? x.x : (__expf(x.x) - 1.f);
  x.y = x.y > 0.f ? x.y : (__expf(x.y) - 1.f);
  x.z = x.z > 0.f ? x.z : (__expf(x.z) - 1.f);
  x.w = x.w > 0.f ? x.w : (__expf(x.w) - 1.f);
  ((float4*)out)[i] = x;
}

extern "C" void kernel_launch(void* const* d_in, const int* in_sizes, int n_in,
                              void* d_out, int out_size, void* d_ws, size_t ws_size,
                              hipStream_t stream) {
  const float* h = (const float*)d_in[0];
  const float* W = (const float*)d_in[1];
  const float* a = (const float*)d_in[2];
  const int* src = (const int*)d_in[3];
  const int* dst = (const int*)d_in[4];
  const int n = in_sizes[0] / IN_DIM;   // 100000
  const int E = in_sizes[3];            // 1600000
  float* out = (float*)d_out;

  char* ws = (char*)d_ws;
  float* z = (float*)ws;                               // n*64 floats
  float* exw = (float*)(ws + (size_t)n * OUT_DIM * 4); // E floats
  float* el = exw + E;                                 // n
  float* er = el + n;                                  // n
  float* ssum = er + n;                                // n (becomes inv_s)

  hipMemsetAsync(ssum, 0, (size_t)n * 4, stream);
  hipMemsetAsync(out, 0, (size_t)n * OUT_DIM * 4, stream);

  k_gemm<<<(n + GB - 1) / GB, GB, 0, stream>>>(h, W, a, z, el, er, n);
  k_edge<<<(E + 255) / 256, 256, 0, stream>>>(src, dst, el, er, exw, ssum, E);
  k_inv<<<(n + 255) / 256, 256, 0, stream>>>(ssum, n);
  {
    long long total = (long long)E * 16;
    k_scatter<<<(int)((total + 255) / 256), 256, 0, stream>>>(src, dst, exw, ssum,
                                                              z, out, E);
  }
  {
    size_t n4 = (size_t)n * OUT_DIM / 4;
    k_elu<<<(int)((n4 + 255) / 256), 256, 0, stream>>>(out, n4);
  }
}

// Round 2
// 592.471 us; speedup vs baseline: 3.2840x; 3.2840x over previous
//
#include <hip/hip_runtime.h>
#include <hip/hip_bf16.h>

#define IN_DIM 256
#define OUT_DIM 64
#define KC 32

// ---------------- GEMM: z = h @ W ; el = z@a1 ; er = z@a2 ----------------
// block = 256 threads, tile = 256 rows x 64 cols.
// thread (tx = t&3, ty = t>>2) computes rows {ty + 64*r} x cols [tx*16, tx*16+16).
__global__ __launch_bounds__(256, 3) void k_gemm(const float* __restrict__ h,
                                                 const float* __restrict__ W,
                                                 const float* __restrict__ a,
                                                 float* __restrict__ z,
                                                 float* __restrict__ el,
                                                 float* __restrict__ er, int n) {
  __shared__ float Hs[256][36];  // stride 36 words: 16B-aligned rows, 2-way max conflict
  __shared__ float Ws[KC][64];
  const int t = threadIdx.x, tx = t & 3, ty = t >> 2;
  const int base = blockIdx.x * 256;

  float acc[4][16];
#pragma unroll
  for (int r = 0; r < 4; ++r)
#pragma unroll
    for (int c = 0; c < 16; ++c) acc[r][c] = 0.f;

  for (int k0 = 0; k0 < IN_DIM; k0 += KC) {
    __syncthreads();
    // stage h: 256 rows x 32 cols = 2048 float4, 8 per thread
#pragma unroll
    for (int i = 0; i < 8; ++i) {
      int f = i * 256 + t, r = f >> 3, j = f & 7;
      int row = base + r;
      float4 v = make_float4(0.f, 0.f, 0.f, 0.f);
      if (row < n) v = *(const float4*)(h + (size_t)row * IN_DIM + k0 + j * 4);
      *(float4*)&Hs[r][j * 4] = v;
    }
    // stage W: 32 x 64 = 512 float4, 2 per thread
#pragma unroll
    for (int i = 0; i < 2; ++i) {
      int f = i * 256 + t, k = f >> 4, j = f & 15;
      *(float4*)&Ws[k][j * 4] = *(const float4*)(W + (size_t)(k0 + k) * OUT_DIM + j * 4);
    }
    __syncthreads();
#pragma unroll
    for (int k = 0; k < KC; k += 4) {
      float4 hv[4];
#pragma unroll
      for (int r = 0; r < 4; ++r) hv[r] = *(const float4*)&Hs[ty + 64 * r][k];
#pragma unroll
      for (int kk = 0; kk < 4; ++kk) {
        const float4 w0 = *(const float4*)&Ws[k + kk][tx * 16 + 0];
        const float4 w1 = *(const float4*)&Ws[k + kk][tx * 16 + 4];
        const float4 w2 = *(const float4*)&Ws[k + kk][tx * 16 + 8];
        const float4 w3 = *(const float4*)&Ws[k + kk][tx * 16 + 12];
#pragma unroll
        for (int r = 0; r < 4; ++r) {
          float hs = kk == 0 ? hv[r].x : kk == 1 ? hv[r].y : kk == 2 ? hv[r].z : hv[r].w;
          acc[r][0] += hs * w0.x;  acc[r][1] += hs * w0.y;
          acc[r][2] += hs * w0.z;  acc[r][3] += hs * w0.w;
          acc[r][4] += hs * w1.x;  acc[r][5] += hs * w1.y;
          acc[r][6] += hs * w1.z;  acc[r][7] += hs * w1.w;
          acc[r][8] += hs * w2.x;  acc[r][9] += hs * w2.y;
          acc[r][10] += hs * w2.z; acc[r][11] += hs * w2.w;
          acc[r][12] += hs * w3.x; acc[r][13] += hs * w3.y;
          acc[r][14] += hs * w3.z; acc[r][15] += hs * w3.w;
        }
      }
    }
  }

  // epilogue: store z; reduce el/er across the 4-lane tx quad
#pragma unroll
  for (int r = 0; r < 4; ++r) {
    int row = base + ty + 64 * r;
    float p1 = 0.f, p2 = 0.f;
#pragma unroll
    for (int c = 0; c < 16; ++c) {
      p1 += acc[r][c] * a[tx * 16 + c];
      p2 += acc[r][c] * a[OUT_DIM + tx * 16 + c];
    }
    p1 += __shfl_xor(p1, 1); p1 += __shfl_xor(p1, 2);
    p2 += __shfl_xor(p2, 1); p2 += __shfl_xor(p2, 2);
    if (row < n) {
      float4* zr = (float4*)(z + (size_t)row * OUT_DIM + tx * 16);
      zr[0] = make_float4(acc[r][0], acc[r][1], acc[r][2], acc[r][3]);
      zr[1] = make_float4(acc[r][4], acc[r][5], acc[r][6], acc[r][7]);
      zr[2] = make_float4(acc[r][8], acc[r][9], acc[r][10], acc[r][11]);
      zr[3] = make_float4(acc[r][12], acc[r][13], acc[r][14], acc[r][15]);
      if (tx == 0) { el[row] = p1; er[row] = p2; }
    }
  }
}

// ---------------- CSR build: histogram -> scan -> place ----------------
__global__ __launch_bounds__(256) void k_hist(const int* __restrict__ dst,
                                              int* __restrict__ deg, int E) {
  int i = blockIdx.x * 256 + threadIdx.x;
  if (i < E) atomicAdd(deg + dst[i], 1);
}

// per-block (1024 elems) exclusive scan; block totals to bsum
__global__ __launch_bounds__(256) void k_scanA(const int* __restrict__ deg,
                                               int* __restrict__ off,
                                               int* __restrict__ bsum, int N) {
  __shared__ int wtot[4];
  int t = threadIdx.x, lane = t & 63, w = t >> 6;
  int idx = blockIdx.x * 1024 + t * 4;
  int d0 = idx + 0 < N ? deg[idx + 0] : 0;
  int d1 = idx + 1 < N ? deg[idx + 1] : 0;
  int d2 = idx + 2 < N ? deg[idx + 2] : 0;
  int d3 = idx + 3 < N ? deg[idx + 3] : 0;
  int tsum = d0 + d1 + d2 + d3;
  int incl = tsum;
  for (int o = 1; o < 64; o <<= 1) {
    int v = __shfl_up(incl, o);
    if (lane >= o) incl += v;
  }
  if (lane == 63) wtot[w] = incl;
  __syncthreads();
  int woff = 0;
  for (int i = 0; i < 4; ++i)
    if (i < w) woff += wtot[i];
  int btot = wtot[0] + wtot[1] + wtot[2] + wtot[3];
  int e = woff + incl - tsum;
  if (idx + 0 < N) off[idx + 0] = e; e += d0;
  if (idx + 1 < N) off[idx + 1] = e; e += d1;
  if (idx + 2 < N) off[idx + 2] = e; e += d2;
  if (idx + 3 < N) off[idx + 3] = e;
  if (t == 0) bsum[blockIdx.x] = btot;
}

__global__ void k_scanB(int* __restrict__ bsum, int nb) {
  int run = 0;
  for (int i = 0; i < nb; ++i) { int v = bsum[i]; bsum[i] = run; run += v; }
}

__global__ __launch_bounds__(256) void k_scanC(int* __restrict__ off,
                                               const int* __restrict__ bsum,
                                               int* __restrict__ cursor, int N, int E) {
  int i = blockIdx.x * 256 + threadIdx.x;
  if (i < N) {
    int v = off[i] + bsum[i >> 10];
    off[i] = v;
    cursor[i] = v;
  }
  if (i == 0) off[N] = E;
}

__global__ __launch_bounds__(256) void k_place(const int* __restrict__ src,
                                               const int* __restrict__ dst,
                                               int* __restrict__ cursor,
                                               int* __restrict__ ssrc, int E) {
  int e = blockIdx.x * 256 + threadIdx.x;
  if (e >= E) return;
  int d = dst[e];
  int pos = atomicAdd(cursor + d, 1);
  ssrc[pos] = src[e];
}

// ------- fused aggregate: softmax-sum + weighted gather + normalize + ELU -------
// 16 lanes per node; lane c handles cols [4c, 4c+4). One write per output row.
__global__ __launch_bounds__(256) void k_agg(const int* __restrict__ off,
                                             const int* __restrict__ ssrc,
                                             const float* __restrict__ el,
                                             const float* __restrict__ er,
                                             const float* __restrict__ z,
                                             float* __restrict__ out, int N) {
  int t = threadIdx.x;
  int node = blockIdx.x * 16 + (t >> 4);
  if (node >= N) return;
  int c = (t & 15) * 4;
  int beg = off[node], end = off[node + 1];
  float erd = er[node];
  float ax = 0.f, ay = 0.f, az = 0.f, aw = 0.f, ssum = 0.f;
  for (int j = beg; j < end; ++j) {
    int s = ssrc[j];
    float x = el[s] + erd;
    x = x > 0.f ? x : 0.01f * x;
    float ex = __expf(x);
    ssum += ex;
    const float4 zv = *(const float4*)(z + (size_t)s * OUT_DIM + c);
    ax += ex * zv.x; ay += ex * zv.y; az += ex * zv.z; aw += ex * zv.w;
  }
  float4 o = make_float4(0.f, 0.f, 0.f, 0.f);
  if (end > beg) {
    float inv = 1.f / ssum;
    ax *= inv; ay *= inv; az *= inv; aw *= inv;
    o.x = ax > 0.f ? ax : __expf(ax) - 1.f;
    o.y = ay > 0.f ? ay : __expf(ay) - 1.f;
    o.z = az > 0.f ? az : __expf(az) - 1.f;
    o.w = aw > 0.f ? aw : __expf(aw) - 1.f;
  }
  *(float4*)(out + (size_t)node * OUT_DIM + c) = o;
}

extern "C" void kernel_launch(void* const* d_in, const int* in_sizes, int n_in,
                              void* d_out, int out_size, void* d_ws, size_t ws_size,
                              hipStream_t stream) {
  const float* h = (const float*)d_in[0];
  const float* W = (const float*)d_in[1];
  const float* a = (const float*)d_in[2];
  const int* src = (const int*)d_in[3];
  const int* dst = (const int*)d_in[4];
  const int n = in_sizes[0] / IN_DIM;  // 100000
  const int E = in_sizes[3];           // 1600000
  float* out = (float*)d_out;

  char* ws = (char*)d_ws;
  float* z = (float*)ws;                       ws += (size_t)n * OUT_DIM * 4;
  float* el = (float*)ws;                      ws += (size_t)n * 4;
  float* er = (float*)ws;                      ws += (size_t)n * 4;
  int* deg = (int*)ws;                         ws += (size_t)n * 4;
  int* off = (int*)ws;                         ws += (size_t)(n + 1) * 4;
  int* cursor = (int*)ws;                      ws += (size_t)n * 4;
  int* bsum = (int*)ws;                        ws += (size_t)256 * 4;
  int* ssrc = (int*)ws;                        ws += (size_t)E * 4;

  const int NB = (n + 1023) / 1024;  // scan blocks

  hipMemsetAsync(deg, 0, (size_t)n * 4, stream);

  k_gemm<<<(n + 255) / 256, 256, 0, stream>>>(h, W, a, z, el, er, n);
  k_hist<<<(E + 255) / 256, 256, 0, stream>>>(dst, deg, E);
  k_scanA<<<NB, 256, 0, stream>>>(deg, off, bsum, n);
  k_scanB<<<1, 1, 0, stream>>>(bsum, NB);
  k_scanC<<<(n + 255) / 256, 256, 0, stream>>>(off, bsum, cursor, n, E);
  k_place<<<(E + 255) / 256, 256, 0, stream>>>(src, dst, cursor, ssrc, E);
  k_agg<<<(n + 15) / 16, 256, 0, stream>>>(off, ssrc, el, er, z, out, n);
}

// Round 3
// 526.809 us; speedup vs baseline: 3.6933x; 1.1246x over previous
//
#include <hip/hip_runtime.h>
#include <hip/hip_bf16.h>

#define IN_DIM 256
#define OUT_DIM 64
#define KC 32
#define ROWS 128  // rows per gemm block

// ---------------- GEMM: z = h @ W ; el = z@a1 ; er = z@a2 ----------------
// 256 threads, tile = 128 rows x 64 cols. tx = t&3 -> cols [tx*16, tx*16+16),
// ty = t>>2 -> rows {ty, ty+64}. acc[2][16] = 32 VGPRs: no spill.
__global__ __launch_bounds__(256, 4) void k_gemm(const float* __restrict__ h,
                                                 const float* __restrict__ W,
                                                 const float* __restrict__ a,
                                                 float* __restrict__ z,
                                                 float* __restrict__ el,
                                                 float* __restrict__ er, int n) {
  __shared__ float Hs[ROWS][36];  // stride 36: 16B-aligned rows, <=2-way bank alias (free)
  __shared__ float Ws[KC][64];
  const int t = threadIdx.x, tx = t & 3, ty = t >> 2;
  const int base = blockIdx.x * ROWS;

  float acc[2][16];
#pragma unroll
  for (int r = 0; r < 2; ++r)
#pragma unroll
    for (int c = 0; c < 16; ++c) acc[r][c] = 0.f;

  float4 ph[4], pw[2];
  // prefetch chunk 0
#pragma unroll
  for (int i = 0; i < 4; ++i) {
    int f = i * 256 + t, r = f >> 3, j = f & 7;
    int row = base + r;
    ph[i] = make_float4(0.f, 0.f, 0.f, 0.f);
    if (row < n) ph[i] = *(const float4*)(h + (size_t)row * IN_DIM + j * 4);
  }
#pragma unroll
  for (int i = 0; i < 2; ++i) {
    int f = i * 256 + t, k = f >> 4, j = f & 15;
    pw[i] = *(const float4*)(W + (size_t)k * OUT_DIM + j * 4);
  }

  for (int k0 = 0; k0 < IN_DIM; k0 += KC) {
    __syncthreads();  // previous chunk's readers done
#pragma unroll
    for (int i = 0; i < 4; ++i) {
      int f = i * 256 + t, r = f >> 3, j = f & 7;
      *(float4*)&Hs[r][j * 4] = ph[i];
    }
#pragma unroll
    for (int i = 0; i < 2; ++i) {
      int f = i * 256 + t, k = f >> 4, j = f & 15;
      *(float4*)&Ws[k][j * 4] = pw[i];
    }
    __syncthreads();

    if (k0 + KC < IN_DIM) {  // prefetch next chunk while computing this one
#pragma unroll
      for (int i = 0; i < 4; ++i) {
        int f = i * 256 + t, r = f >> 3, j = f & 7;
        int row = base + r;
        ph[i] = make_float4(0.f, 0.f, 0.f, 0.f);
        if (row < n)
          ph[i] = *(const float4*)(h + (size_t)row * IN_DIM + (k0 + KC) + j * 4);
      }
#pragma unroll
      for (int i = 0; i < 2; ++i) {
        int f = i * 256 + t, k = f >> 4, j = f & 15;
        pw[i] = *(const float4*)(W + (size_t)(k0 + KC + k) * OUT_DIM + j * 4);
      }
    }

#pragma unroll
    for (int kk = 0; kk < KC / 4; ++kk) {
      const float4 ha = *(const float4*)&Hs[ty][kk * 4];
      const float4 hb = *(const float4*)&Hs[ty + 64][kk * 4];
#pragma unroll
      for (int j = 0; j < 4; ++j) {
        const float4 w0 = *(const float4*)&Ws[kk * 4 + j][tx * 16 + 0];
        const float4 w1 = *(const float4*)&Ws[kk * 4 + j][tx * 16 + 4];
        const float4 w2 = *(const float4*)&Ws[kk * 4 + j][tx * 16 + 8];
        const float4 w3 = *(const float4*)&Ws[kk * 4 + j][tx * 16 + 12];
        const float sa = j == 0 ? ha.x : j == 1 ? ha.y : j == 2 ? ha.z : ha.w;
        const float sb = j == 0 ? hb.x : j == 1 ? hb.y : j == 2 ? hb.z : hb.w;
        acc[0][0] += sa * w0.x;  acc[0][1] += sa * w0.y;
        acc[0][2] += sa * w0.z;  acc[0][3] += sa * w0.w;
        acc[0][4] += sa * w1.x;  acc[0][5] += sa * w1.y;
        acc[0][6] += sa * w1.z;  acc[0][7] += sa * w1.w;
        acc[0][8] += sa * w2.x;  acc[0][9] += sa * w2.y;
        acc[0][10] += sa * w2.z; acc[0][11] += sa * w2.w;
        acc[0][12] += sa * w3.x; acc[0][13] += sa * w3.y;
        acc[0][14] += sa * w3.z; acc[0][15] += sa * w3.w;
        acc[1][0] += sb * w0.x;  acc[1][1] += sb * w0.y;
        acc[1][2] += sb * w0.z;  acc[1][3] += sb * w0.w;
        acc[1][4] += sb * w1.x;  acc[1][5] += sb * w1.y;
        acc[1][6] += sb * w1.z;  acc[1][7] += sb * w1.w;
        acc[1][8] += sb * w2.x;  acc[1][9] += sb * w2.y;
        acc[1][10] += sb * w2.z; acc[1][11] += sb * w2.w;
        acc[1][12] += sb * w3.x; acc[1][13] += sb * w3.y;
        acc[1][14] += sb * w3.z; acc[1][15] += sb * w3.w;
      }
    }
  }

  // epilogue: store z rows; quad-reduce el/er (tx = lanes 0..3 of each quad)
#pragma unroll
  for (int r = 0; r < 2; ++r) {
    int row = base + ty + 64 * r;
    float p1 = 0.f, p2 = 0.f;
#pragma unroll
    for (int c = 0; c < 16; ++c) {
      p1 += acc[r][c] * a[tx * 16 + c];
      p2 += acc[r][c] * a[OUT_DIM + tx * 16 + c];
    }
    p1 += __shfl_xor(p1, 1); p1 += __shfl_xor(p1, 2);
    p2 += __shfl_xor(p2, 1); p2 += __shfl_xor(p2, 2);
    if (row < n) {
      float4* zr = (float4*)(z + (size_t)row * OUT_DIM + tx * 16);
      zr[0] = make_float4(acc[r][0], acc[r][1], acc[r][2], acc[r][3]);
      zr[1] = make_float4(acc[r][4], acc[r][5], acc[r][6], acc[r][7]);
      zr[2] = make_float4(acc[r][8], acc[r][9], acc[r][10], acc[r][11]);
      zr[3] = make_float4(acc[r][12], acc[r][13], acc[r][14], acc[r][15]);
      if (tx == 0) { el[row] = p1; er[row] = p2; }
    }
  }
}

// ---------------- CSR build: histogram -> scan -> place ----------------
__global__ __launch_bounds__(256) void k_hist(const int* __restrict__ dst,
                                              int* __restrict__ deg, int E) {
  int i = blockIdx.x * 256 + threadIdx.x;
  if (i < E) atomicAdd(deg + dst[i], 1);
}

// per-block (1024 elems) exclusive scan; block totals to bsum
__global__ __launch_bounds__(256) void k_scanA(const int* __restrict__ deg,
                                               int* __restrict__ off,
                                               int* __restrict__ bsum, int N) {
  __shared__ int wtot[4];
  int t = threadIdx.x, lane = t & 63, w = t >> 6;
  int idx = blockIdx.x * 1024 + t * 4;
  int d0 = idx + 0 < N ? deg[idx + 0] : 0;
  int d1 = idx + 1 < N ? deg[idx + 1] : 0;
  int d2 = idx + 2 < N ? deg[idx + 2] : 0;
  int d3 = idx + 3 < N ? deg[idx + 3] : 0;
  int tsum = d0 + d1 + d2 + d3;
  int incl = tsum;
  for (int o = 1; o < 64; o <<= 1) {
    int v = __shfl_up(incl, o);
    if (lane >= o) incl += v;
  }
  if (lane == 63) wtot[w] = incl;
  __syncthreads();
  int woff = 0;
  for (int i = 0; i < 4; ++i)
    if (i < w) woff += wtot[i];
  int btot = wtot[0] + wtot[1] + wtot[2] + wtot[3];
  int e = woff + incl - tsum;
  if (idx + 0 < N) off[idx + 0] = e; e += d0;
  if (idx + 1 < N) off[idx + 1] = e; e += d1;
  if (idx + 2 < N) off[idx + 2] = e; e += d2;
  if (idx + 3 < N) off[idx + 3] = e;
  if (t == 0) bsum[blockIdx.x] = btot;
}

// one-block exclusive scan over nb (<=256) block totals
__global__ __launch_bounds__(256) void k_scanB(int* __restrict__ bsum, int nb) {
  __shared__ int wtot[4];
  int t = threadIdx.x, lane = t & 63, w = t >> 6;
  int v = t < nb ? bsum[t] : 0;
  int incl = v;
  for (int o = 1; o < 64; o <<= 1) {
    int u = __shfl_up(incl, o);
    if (lane >= o) incl += u;
  }
  if (lane == 63) wtot[w] = incl;
  __syncthreads();
  int woff = 0;
  for (int i = 0; i < 4; ++i)
    if (i < w) woff += wtot[i];
  if (t < nb) bsum[t] = woff + incl - v;
}

__global__ __launch_bounds__(256) void k_scanC(int* __restrict__ off,
                                               const int* __restrict__ bsum,
                                               int* __restrict__ cursor, int N, int E) {
  int i = blockIdx.x * 256 + threadIdx.x;
  if (i < N) {
    int v = off[i] + bsum[i >> 10];
    off[i] = v;
    cursor[i] = v;
  }
  if (i == 0) off[N] = E;
}

__global__ __launch_bounds__(256) void k_place(const int* __restrict__ src,
                                               const int* __restrict__ dst,
                                               int* __restrict__ cursor,
                                               int* __restrict__ ssrc, int E) {
  int e = blockIdx.x * 256 + threadIdx.x;
  if (e >= E) return;
  int d = dst[e];
  int pos = atomicAdd(cursor + d, 1);
  ssrc[pos] = src[e];
}

// ------- fused aggregate: softmax-sum + weighted gather + normalize + ELU -------
// 16 lanes per node; lane c handles cols [4c, 4c+4). One write per output row.
__global__ __launch_bounds__(256) void k_agg(const int* __restrict__ off,
                                             const int* __restrict__ ssrc,
                                             const float* __restrict__ el,
                                             const float* __restrict__ er,
                                             const float* __restrict__ z,
                                             float* __restrict__ out, int N) {
  int t = threadIdx.x;
  int node = blockIdx.x * 16 + (t >> 4);
  if (node >= N) return;
  int c = (t & 15) * 4;
  int beg = off[node], end = off[node + 1];
  float erd = er[node];
  float ax = 0.f, ay = 0.f, az = 0.f, aw = 0.f, ssum = 0.f;
  for (int j = beg; j < end; ++j) {
    int s = ssrc[j];
    float x = el[s] + erd;
    x = x > 0.f ? x : 0.01f * x;
    float ex = __expf(x);
    ssum += ex;
    const float4 zv = *(const float4*)(z + (size_t)s * OUT_DIM + c);
    ax += ex * zv.x; ay += ex * zv.y; az += ex * zv.z; aw += ex * zv.w;
  }
  float4 o = make_float4(0.f, 0.f, 0.f, 0.f);
  if (end > beg) {
    float inv = 1.f / ssum;
    ax *= inv; ay *= inv; az *= inv; aw *= inv;
    o.x = ax > 0.f ? ax : __expf(ax) - 1.f;
    o.y = ay > 0.f ? ay : __expf(ay) - 1.f;
    o.z = az > 0.f ? az : __expf(az) - 1.f;
    o.w = aw > 0.f ? aw : __expf(aw) - 1.f;
  }
  *(float4*)(out + (size_t)node * OUT_DIM + c) = o;
}

extern "C" void kernel_launch(void* const* d_in, const int* in_sizes, int n_in,
                              void* d_out, int out_size, void* d_ws, size_t ws_size,
                              hipStream_t stream) {
  const float* h = (const float*)d_in[0];
  const float* W = (const float*)d_in[1];
  const float* a = (const float*)d_in[2];
  const int* src = (const int*)d_in[3];
  const int* dst = (const int*)d_in[4];
  const int n = in_sizes[0] / IN_DIM;  // 100000
  const int E = in_sizes[3];           // 1600000
  float* out = (float*)d_out;

  char* ws = (char*)d_ws;
  float* z = (float*)ws;                       ws += (size_t)n * OUT_DIM * 4;
  float* el = (float*)ws;                      ws += (size_t)n * 4;
  float* er = (float*)ws;                      ws += (size_t)n * 4;
  int* deg = (int*)ws;                         ws += (size_t)n * 4;
  int* off = (int*)ws;                         ws += (size_t)(n + 1) * 4;
  int* cursor = (int*)ws;                      ws += (size_t)n * 4;
  int* bsum = (int*)ws;                        ws += (size_t)256 * 4;
  int* ssrc = (int*)ws;                        ws += (size_t)E * 4;

  const int NB = (n + 1023) / 1024;  // scan blocks (98 for n=100000, <=256)

  hipMemsetAsync(deg, 0, (size_t)n * 4, stream);

  k_gemm<<<(n + ROWS - 1) / ROWS, 256, 0, stream>>>(h, W, a, z, el, er, n);
  k_hist<<<(E + 255) / 256, 256, 0, stream>>>(dst, deg, E);
  k_scanA<<<NB, 256, 0, stream>>>(deg, off, bsum, n);
  k_scanB<<<1, 256, 0, stream>>>(bsum, NB);
  k_scanC<<<(n + 255) / 256, 256, 0, stream>>>(off, bsum, cursor, n, E);
  k_place<<<(E + 255) / 256, 256, 0, stream>>>(src, dst, cursor, ssrc, E);
  k_agg<<<(n + 15) / 16, 256, 0, stream>>>(off, ssrc, el, er, z, out, n);
}

// Round 4
// 454.672 us; speedup vs baseline: 4.2793x; 1.1587x over previous
//
#include <hip/hip_runtime.h>
#include <hip/hip_bf16.h>

#define IN_DIM 256
#define OUT_DIM 64
#define AST 264  // LDS K-stride in ushorts: 16B-aligned rows, balanced bank windows

typedef short bf16x8 __attribute__((ext_vector_type(8)));
typedef float f32x4 __attribute__((ext_vector_type(4)));

__device__ inline unsigned short f2bf(float x) {
  unsigned int u = __float_as_uint(x);
  return (unsigned short)((u + 0x7FFFu + ((u >> 16) & 1u)) >> 16);
}

// ---------------- GEMM: z = h @ W ; el = z@a1 ; er = z@a2 (MFMA bf16) --------
// 256 threads = 4 waves; tile 64 rows x 64 cols; wave w -> rows w*16..w*16+15.
// Full K=256 staged once in LDS (bf16). acc = 4 x f32x4 per lane: no spill.
__global__ __launch_bounds__(256) void k_gemm(const float* __restrict__ h,
                                              const float* __restrict__ W,
                                              const float* __restrict__ a,
                                              float* __restrict__ z,
                                              float* __restrict__ el,
                                              float* __restrict__ er, int n) {
  __shared__ unsigned short Ab[64][AST];  // h tile, bf16, [row][k]
  __shared__ unsigned short Wt[64][AST];  // W transposed, bf16, [col][k]
  const int t = threadIdx.x;
  const int base = blockIdx.x * 64;

  // stage W -> Wt (transpose + cvt). 4096 float4, 16/thread, coalesced reads.
#pragma unroll
  for (int i = 0; i < 16; ++i) {
    int f = i * 256 + t;
    int k = f >> 4, n0 = (f & 15) * 4;
    float4 v = *(const float4*)(W + (size_t)f * 4);
    Wt[n0 + 0][k] = f2bf(v.x);
    Wt[n0 + 1][k] = f2bf(v.y);
    Wt[n0 + 2][k] = f2bf(v.z);
    Wt[n0 + 3][k] = f2bf(v.w);
  }
  // stage h tile -> Ab (cvt). 4096 float4, 16/thread, coalesced.
#pragma unroll
  for (int i = 0; i < 16; ++i) {
    int f = i * 256 + t;
    int r = f >> 6, c4 = f & 63;
    int row = base + r;
    float4 v = make_float4(0.f, 0.f, 0.f, 0.f);
    if (row < n) v = *(const float4*)(h + (size_t)row * IN_DIM + c4 * 4);
    unsigned int p0 = (unsigned int)f2bf(v.x) | ((unsigned int)f2bf(v.y) << 16);
    unsigned int p1 = (unsigned int)f2bf(v.z) | ((unsigned int)f2bf(v.w) << 16);
    *(uint2*)&Ab[r][c4 * 4] = make_uint2(p0, p1);  // 8B-aligned
  }
  __syncthreads();

  const int w = t >> 6, lane = t & 63;
  const int nq = lane & 15, q = lane >> 4;

  f32x4 acc[4];
#pragma unroll
  for (int ct = 0; ct < 4; ++ct) acc[ct] = (f32x4){0.f, 0.f, 0.f, 0.f};

#pragma unroll
  for (int kc = 0; kc < 8; ++kc) {
    const int k0 = kc * 32 + q * 8;  // 16B-aligned within row
    bf16x8 af = *(const bf16x8*)&Ab[w * 16 + nq][k0];
#pragma unroll
    for (int ct = 0; ct < 4; ++ct) {
      bf16x8 bfr = *(const bf16x8*)&Wt[ct * 16 + nq][k0];
      acc[ct] = __builtin_amdgcn_mfma_f32_16x16x32_bf16(af, bfr, acc[ct], 0, 0, 0);
    }
  }

  // epilogue. C/D layout: col = ct*16 + nq, row (within wave tile) = q*4 + r.
  float a1[4], a2[4];
#pragma unroll
  for (int ct = 0; ct < 4; ++ct) {
    a1[ct] = a[ct * 16 + nq];
    a2[ct] = a[OUT_DIM + ct * 16 + nq];
  }
#pragma unroll
  for (int r = 0; r < 4; ++r) {
    int row = base + w * 16 + q * 4 + r;
    float p1 = 0.f, p2 = 0.f;
#pragma unroll
    for (int ct = 0; ct < 4; ++ct) {
      float v = acc[ct][r];
      p1 += v * a1[ct];
      p2 += v * a2[ct];
      if (row < n) z[(size_t)row * OUT_DIM + ct * 16 + nq] = v;
    }
    p1 += __shfl_xor(p1, 1); p1 += __shfl_xor(p1, 2);
    p1 += __shfl_xor(p1, 4); p1 += __shfl_xor(p1, 8);
    p2 += __shfl_xor(p2, 1); p2 += __shfl_xor(p2, 2);
    p2 += __shfl_xor(p2, 4); p2 += __shfl_xor(p2, 8);
    if (row < n && nq == 0) { el[row] = p1; er[row] = p2; }
  }
}

// ---------------- CSR build: histogram -> scan -> place ----------------
__global__ __launch_bounds__(256) void k_hist(const int* __restrict__ dst,
                                              int* __restrict__ deg, int E) {
  int i = blockIdx.x * 256 + threadIdx.x;
  if (i < E) atomicAdd(deg + dst[i], 1);
}

__global__ __launch_bounds__(256) void k_scanA(const int* __restrict__ deg,
                                               int* __restrict__ off,
                                               int* __restrict__ bsum, int N) {
  __shared__ int wtot[4];
  int t = threadIdx.x, lane = t & 63, w = t >> 6;
  int idx = blockIdx.x * 1024 + t * 4;
  int d0 = idx + 0 < N ? deg[idx + 0] : 0;
  int d1 = idx + 1 < N ? deg[idx + 1] : 0;
  int d2 = idx + 2 < N ? deg[idx + 2] : 0;
  int d3 = idx + 3 < N ? deg[idx + 3] : 0;
  int tsum = d0 + d1 + d2 + d3;
  int incl = tsum;
  for (int o = 1; o < 64; o <<= 1) {
    int v = __shfl_up(incl, o);
    if (lane >= o) incl += v;
  }
  if (lane == 63) wtot[w] = incl;
  __syncthreads();
  int woff = 0;
  for (int i = 0; i < 4; ++i)
    if (i < w) woff += wtot[i];
  int btot = wtot[0] + wtot[1] + wtot[2] + wtot[3];
  int e = woff + incl - tsum;
  if (idx + 0 < N) off[idx + 0] = e; e += d0;
  if (idx + 1 < N) off[idx + 1] = e; e += d1;
  if (idx + 2 < N) off[idx + 2] = e; e += d2;
  if (idx + 3 < N) off[idx + 3] = e;
  if (t == 0) bsum[blockIdx.x] = btot;
}

__global__ __launch_bounds__(256) void k_scanB(int* __restrict__ bsum, int nb) {
  __shared__ int wtot[4];
  int t = threadIdx.x, lane = t & 63, w = t >> 6;
  int v = t < nb ? bsum[t] : 0;
  int incl = v;
  for (int o = 1; o < 64; o <<= 1) {
    int u = __shfl_up(incl, o);
    if (lane >= o) incl += u;
  }
  if (lane == 63) wtot[w] = incl;
  __syncthreads();
  int woff = 0;
  for (int i = 0; i < 4; ++i)
    if (i < w) woff += wtot[i];
  if (t < nb) bsum[t] = woff + incl - v;
}

__global__ __launch_bounds__(256) void k_scanC(int* __restrict__ off,
                                               const int* __restrict__ bsum,
                                               int* __restrict__ cursor, int N, int E) {
  int i = blockIdx.x * 256 + threadIdx.x;
  if (i < N) {
    int v = off[i] + bsum[i >> 10];
    off[i] = v;
    cursor[i] = v;
  }
  if (i == 0) off[N] = E;
}

__global__ __launch_bounds__(256) void k_place(const int* __restrict__ src,
                                               const int* __restrict__ dst,
                                               int* __restrict__ cursor,
                                               int* __restrict__ ssrc, int E) {
  int e = blockIdx.x * 256 + threadIdx.x;
  if (e >= E) return;
  int d = dst[e];
  int pos = atomicAdd(cursor + d, 1);
  ssrc[pos] = src[e];
}

// ------- fused aggregate: softmax-sum + weighted gather + normalize + ELU -------
__global__ __launch_bounds__(256) void k_agg(const int* __restrict__ off,
                                             const int* __restrict__ ssrc,
                                             const float* __restrict__ el,
                                             const float* __restrict__ er,
                                             const float* __restrict__ z,
                                             float* __restrict__ out, int N) {
  int t = threadIdx.x;
  int node = blockIdx.x * 16 + (t >> 4);
  if (node >= N) return;
  int c = (t & 15) * 4;
  int beg = off[node], end = off[node + 1];
  float erd = er[node];
  float ax = 0.f, ay = 0.f, az = 0.f, aw = 0.f, ssum = 0.f;
  for (int j = beg; j < end; ++j) {
    int s = ssrc[j];
    float x = el[s] + erd;
    x = x > 0.f ? x : 0.01f * x;
    float ex = __expf(x);
    ssum += ex;
    const float4 zv = *(const float4*)(z + (size_t)s * OUT_DIM + c);
    ax += ex * zv.x; ay += ex * zv.y; az += ex * zv.z; aw += ex * zv.w;
  }
  float4 o = make_float4(0.f, 0.f, 0.f, 0.f);
  if (end > beg) {
    float inv = 1.f / ssum;
    ax *= inv; ay *= inv; az *= inv; aw *= inv;
    o.x = ax > 0.f ? ax : __expf(ax) - 1.f;
    o.y = ay > 0.f ? ay : __expf(ay) - 1.f;
    o.z = az > 0.f ? az : __expf(az) - 1.f;
    o.w = aw > 0.f ? aw : __expf(aw) - 1.f;
  }
  *(float4*)(out + (size_t)node * OUT_DIM + c) = o;
}

extern "C" void kernel_launch(void* const* d_in, const int* in_sizes, int n_in,
                              void* d_out, int out_size, void* d_ws, size_t ws_size,
                              hipStream_t stream) {
  const float* h = (const float*)d_in[0];
  const float* W = (const float*)d_in[1];
  const float* a = (const float*)d_in[2];
  const int* src = (const int*)d_in[3];
  const int* dst = (const int*)d_in[4];
  const int n = in_sizes[0] / IN_DIM;  // 100000
  const int E = in_sizes[3];           // 1600000
  float* out = (float*)d_out;

  char* ws = (char*)d_ws;
  float* z = (float*)ws;                       ws += (size_t)n * OUT_DIM * 4;
  float* el = (float*)ws;                      ws += (size_t)n * 4;
  float* er = (float*)ws;                      ws += (size_t)n * 4;
  int* deg = (int*)ws;                         ws += (size_t)n * 4;
  int* off = (int*)ws;                         ws += (size_t)(n + 1) * 4;
  int* cursor = (int*)ws;                      ws += (size_t)n * 4;
  int* bsum = (int*)ws;                        ws += (size_t)256 * 4;
  int* ssrc = (int*)ws;                        ws += (size_t)E * 4;

  const int NB = (n + 1023) / 1024;  // 98 blocks, <=256

  hipMemsetAsync(deg, 0, (size_t)n * 4, stream);

  k_gemm<<<(n + 63) / 64, 256, 0, stream>>>(h, W, a, z, el, er, n);
  k_hist<<<(E + 255) / 256, 256, 0, stream>>>(dst, deg, E);
  k_scanA<<<NB, 256, 0, stream>>>(deg, off, bsum, n);
  k_scanB<<<1, 256, 0, stream>>>(bsum, NB);
  k_scanC<<<(n + 255) / 256, 256, 0, stream>>>(off, bsum, cursor, n, E);
  k_place<<<(E + 255) / 256, 256, 0, stream>>>(src, dst, cursor, ssrc, E);
  k_agg<<<(n + 15) / 16, 256, 0, stream>>>(off, ssrc, el, er, z, out, n);
}

// Round 5
// 328.056 us; speedup vs baseline: 5.9309x; 1.3860x over previous
//
#include <hip/hip_runtime.h>
#include <hip/hip_bf16.h>

#define IN_DIM 256
#define OUT_DIM 64
#define AST 264   // gemm LDS K-stride (ushorts)
#define CHUNK 8192
#define BSH 9     // bucket = dst >> 9  (512 nodes per bucket)
#define P2CAP 12288

typedef short bf16x8 __attribute__((ext_vector_type(8)));
typedef float f32x4 __attribute__((ext_vector_type(4)));

__device__ inline unsigned short f2bf(float x) {
  unsigned int u = __float_as_uint(x);
  return (unsigned short)((u + 0x7FFFu + ((u >> 16) & 1u)) >> 16);
}

// ---------------- GEMM: z = h @ W ; el = z@a1 ; er = z@a2 (MFMA bf16) --------
__global__ __launch_bounds__(256) void k_gemm(const float* __restrict__ h,
                                              const float* __restrict__ W,
                                              const float* __restrict__ a,
                                              float* __restrict__ z,
                                              float* __restrict__ el,
                                              float* __restrict__ er, int n) {
  __shared__ unsigned short Ab[64][AST];
  __shared__ unsigned short Wt[64][AST];
  const int t = threadIdx.x;
  const int base = blockIdx.x * 64;

#pragma unroll
  for (int i = 0; i < 16; ++i) {
    int f = i * 256 + t;
    int k = f >> 4, n0 = (f & 15) * 4;
    float4 v = *(const float4*)(W + (size_t)f * 4);
    Wt[n0 + 0][k] = f2bf(v.x);
    Wt[n0 + 1][k] = f2bf(v.y);
    Wt[n0 + 2][k] = f2bf(v.z);
    Wt[n0 + 3][k] = f2bf(v.w);
  }
#pragma unroll
  for (int i = 0; i < 16; ++i) {
    int f = i * 256 + t;
    int r = f >> 6, c4 = f & 63;
    int row = base + r;
    float4 v = make_float4(0.f, 0.f, 0.f, 0.f);
    if (row < n) v = *(const float4*)(h + (size_t)row * IN_DIM + c4 * 4);
    unsigned int p0 = (unsigned int)f2bf(v.x) | ((unsigned int)f2bf(v.y) << 16);
    unsigned int p1 = (unsigned int)f2bf(v.z) | ((unsigned int)f2bf(v.w) << 16);
    *(uint2*)&Ab[r][c4 * 4] = make_uint2(p0, p1);
  }
  __syncthreads();

  const int w = t >> 6, lane = t & 63;
  const int nq = lane & 15, q = lane >> 4;

  f32x4 acc[4];
#pragma unroll
  for (int ct = 0; ct < 4; ++ct) acc[ct] = (f32x4){0.f, 0.f, 0.f, 0.f};

#pragma unroll
  for (int kc = 0; kc < 8; ++kc) {
    const int k0 = kc * 32 + q * 8;
    bf16x8 af = *(const bf16x8*)&Ab[w * 16 + nq][k0];
#pragma unroll
    for (int ct = 0; ct < 4; ++ct) {
      bf16x8 bfr = *(const bf16x8*)&Wt[ct * 16 + nq][k0];
      acc[ct] = __builtin_amdgcn_mfma_f32_16x16x32_bf16(af, bfr, acc[ct], 0, 0, 0);
    }
  }

  float a1[4], a2[4];
#pragma unroll
  for (int ct = 0; ct < 4; ++ct) {
    a1[ct] = a[ct * 16 + nq];
    a2[ct] = a[OUT_DIM + ct * 16 + nq];
  }
#pragma unroll
  for (int r = 0; r < 4; ++r) {
    int row = base + w * 16 + q * 4 + r;
    float p1 = 0.f, p2 = 0.f;
#pragma unroll
    for (int ct = 0; ct < 4; ++ct) {
      float v = acc[ct][r];
      p1 += v * a1[ct];
      p2 += v * a2[ct];
      if (row < n) z[(size_t)row * OUT_DIM + ct * 16 + nq] = v;
    }
    p1 += __shfl_xor(p1, 1); p1 += __shfl_xor(p1, 2);
    p1 += __shfl_xor(p1, 4); p1 += __shfl_xor(p1, 8);
    p2 += __shfl_xor(p2, 1); p2 += __shfl_xor(p2, 2);
    p2 += __shfl_xor(p2, 4); p2 += __shfl_xor(p2, 8);
    if (row < n && nq == 0) { el[row] = p1; er[row] = p2; }
  }
}

// ------------- pass-1: per-block per-bucket histogram (bucket-major out) -----
__global__ __launch_bounds__(256) void k_p1hist(const int* __restrict__ dst,
                                                int* __restrict__ gh, int E,
                                                int nbuck, int b1) {
  __shared__ int hist[256];
  int t = threadIdx.x, b = blockIdx.x;
  hist[t] = 0;
  __syncthreads();
  int beg = b * CHUNK;
  for (int i = t; i < CHUNK; i += 256) {
    int e = beg + i;
    if (e < E) atomicAdd(&hist[dst[e] >> BSH], 1);
  }
  __syncthreads();
  if (t < nbuck) gh[t * b1 + b] = hist[t];
}

// ------------- generic scan: per-block (1024) exclusive + block totals -------
__global__ __launch_bounds__(256) void k_scanA(const int* __restrict__ in,
                                               int* __restrict__ out,
                                               int* __restrict__ bsum, int N) {
  __shared__ int wtot[4];
  int t = threadIdx.x, lane = t & 63, w = t >> 6;
  int idx = blockIdx.x * 1024 + t * 4;
  int d0 = idx + 0 < N ? in[idx + 0] : 0;
  int d1 = idx + 1 < N ? in[idx + 1] : 0;
  int d2 = idx + 2 < N ? in[idx + 2] : 0;
  int d3 = idx + 3 < N ? in[idx + 3] : 0;
  int tsum = d0 + d1 + d2 + d3;
  int incl = tsum;
  for (int o = 1; o < 64; o <<= 1) {
    int v = __shfl_up(incl, o);
    if (lane >= o) incl += v;
  }
  if (lane == 63) wtot[w] = incl;
  __syncthreads();
  int woff = 0;
  for (int i = 0; i < 4; ++i)
    if (i < w) woff += wtot[i];
  int btot = wtot[0] + wtot[1] + wtot[2] + wtot[3];
  int e = woff + incl - tsum;
  if (idx + 0 < N) out[idx + 0] = e; e += d0;
  if (idx + 1 < N) out[idx + 1] = e; e += d1;
  if (idx + 2 < N) out[idx + 2] = e; e += d2;
  if (idx + 3 < N) out[idx + 3] = e;
  if (t == 0) bsum[blockIdx.x] = btot;
}

__global__ __launch_bounds__(256) void k_scanB(int* __restrict__ bsum, int nb) {
  __shared__ int wtot[4];
  int t = threadIdx.x, lane = t & 63, w = t >> 6;
  int v = t < nb ? bsum[t] : 0;
  int incl = v;
  for (int o = 1; o < 64; o <<= 1) {
    int u = __shfl_up(incl, o);
    if (lane >= o) incl += u;
  }
  if (lane == 63) wtot[w] = incl;
  __syncthreads();
  int woff = 0;
  for (int i = 0; i < 4; ++i)
    if (i < w) woff += wtot[i];
  if (t < nb) bsum[t] = woff + incl - v;
}

__global__ __launch_bounds__(256) void k_scanC2(int* __restrict__ out,
                                                const int* __restrict__ bsum, int M) {
  int i = blockIdx.x * 256 + threadIdx.x;
  if (i < M) out[i] += bsum[i >> 10];
}

// ------------- pass-1 scatter: partition (dst,src) by bucket, dense runs -----
__global__ __launch_bounds__(256) void k_p1scat(const int* __restrict__ src,
                                                const int* __restrict__ dst,
                                                const int* __restrict__ pbase,
                                                int2* __restrict__ pairs, int E,
                                                int nbuck, int b1) {
  __shared__ int pb[256];
  __shared__ int cur[256];
  int t = threadIdx.x, b = blockIdx.x;
  if (t < nbuck) pb[t] = pbase[t * b1 + b];
  cur[t] = 0;
  __syncthreads();
  int beg = b * CHUNK;
  for (int i = t; i < CHUNK; i += 256) {
    int e = beg + i;
    if (e < E) {
      int d = dst[e], s = src[e];
      int bk = d >> BSH;
      int r = atomicAdd(&cur[bk], 1);
      pairs[pb[bk] + r] = make_int2(d, s);
    }
  }
}

// ------------- pass-2: per-bucket in-LDS counting sort + off[] emit ----------
__global__ __launch_bounds__(256) void k_p2(const int2* __restrict__ pairs,
                                            const int* __restrict__ pbase,
                                            int* __restrict__ ssrc,
                                            int* __restrict__ off, int E, int n,
                                            int nbuck, int b1) {
  __shared__ int deg[512];
  __shared__ int loff[512];
  __shared__ int cur[512];
  __shared__ int stage[P2CAP];
  __shared__ int wtot[4];
  int t = threadIdx.x, b = blockIdx.x;
  int beg = pbase[b * b1];
  int end = (b + 1 < nbuck) ? pbase[(b + 1) * b1] : E;
  int cnt = end - beg;
  int base = b << BSH;
  deg[t] = 0;
  deg[t + 256] = 0;
  __syncthreads();
  for (int i = t; i < cnt; i += 256) atomicAdd(&deg[pairs[beg + i].x - base], 1);
  __syncthreads();
  // exclusive scan of deg[512] (2 elems/thread + wave scan)
  int a0 = deg[2 * t], a1 = deg[2 * t + 1];
  int ps = a0 + a1;
  int lane = t & 63, w = t >> 6;
  int inc = ps;
  for (int o = 1; o < 64; o <<= 1) {
    int v = __shfl_up(inc, o);
    if (lane >= o) inc += v;
  }
  if (lane == 63) wtot[w] = inc;
  __syncthreads();
  int woff = 0;
  for (int i = 0; i < 4; ++i)
    if (i < w) woff += wtot[i];
  int ex = woff + inc - ps;
  loff[2 * t] = ex;
  loff[2 * t + 1] = ex + a0;
  cur[2 * t] = ex;
  cur[2 * t + 1] = ex + a0;
  __syncthreads();
  for (int i = t; i < cnt; i += 256) {
    int2 p = pairs[beg + i];
    int r = atomicAdd(&cur[p.x - base], 1);
    if (r < P2CAP) stage[r] = p.y;
  }
  __syncthreads();
  for (int i = t; i < cnt; i += 256) ssrc[beg + i] = stage[i];
  for (int i = t; i < 512; i += 256) {
    int node = base + i;
    if (node <= n) off[node] = beg + loff[i];
  }
}

// ------- fused aggregate: softmax-sum + weighted gather + normalize + ELU -------
__global__ __launch_bounds__(256) void k_agg(const int* __restrict__ off,
                                             const int* __restrict__ ssrc,
                                             const float* __restrict__ el,
                                             const float* __restrict__ er,
                                             const float* __restrict__ z,
                                             float* __restrict__ out, int N) {
  int t = threadIdx.x;
  int node = blockIdx.x * 16 + (t >> 4);
  if (node >= N) return;
  int c = (t & 15) * 4;
  int beg = off[node], end = off[node + 1];
  float erd = er[node];
  float ax = 0.f, ay = 0.f, az = 0.f, aw = 0.f, ssum = 0.f;
  for (int j = beg; j < end; ++j) {
    int s = ssrc[j];
    float x = el[s] + erd;
    x = x > 0.f ? x : 0.01f * x;
    float ex = __expf(x);
    ssum += ex;
    const float4 zv = *(const float4*)(z + (size_t)s * OUT_DIM + c);
    ax += ex * zv.x; ay += ex * zv.y; az += ex * zv.z; aw += ex * zv.w;
  }
  float4 o = make_float4(0.f, 0.f, 0.f, 0.f);
  if (end > beg) {
    float inv = 1.f / ssum;
    ax *= inv; ay *= inv; az *= inv; aw *= inv;
    o.x = ax > 0.f ? ax : __expf(ax) - 1.f;
    o.y = ay > 0.f ? ay : __expf(ay) - 1.f;
    o.z = az > 0.f ? az : __expf(az) - 1.f;
    o.w = aw > 0.f ? aw : __expf(aw) - 1.f;
  }
  *(float4*)(out + (size_t)node * OUT_DIM + c) = o;
}

extern "C" void kernel_launch(void* const* d_in, const int* in_sizes, int n_in,
                              void* d_out, int out_size, void* d_ws, size_t ws_size,
                              hipStream_t stream) {
  const float* h = (const float*)d_in[0];
  const float* W = (const float*)d_in[1];
  const float* a = (const float*)d_in[2];
  const int* src = (const int*)d_in[3];
  const int* dst = (const int*)d_in[4];
  const int n = in_sizes[0] / IN_DIM;  // 100000
  const int E = in_sizes[3];           // 1600000
  float* out = (float*)d_out;

  const int b1 = (E + CHUNK - 1) / CHUNK;       // 196
  const int nbuck = (n + (1 << BSH) - 1) >> BSH;  // 196
  const int M = nbuck * b1;                     // 38416
  const int NB = (M + 1023) / 1024;             // 38

  char* ws = (char*)d_ws;
  float* z = (float*)ws;      ws += (size_t)n * OUT_DIM * 4;
  float* el = (float*)ws;     ws += (size_t)n * 4;
  float* er = (float*)ws;     ws += (size_t)n * 4;
  int* gh = (int*)ws;         ws += (size_t)M * 4;
  int* pbase = (int*)ws;      ws += (size_t)M * 4;
  int* bsum = (int*)ws;       ws += (size_t)256 * 4;
  int* off = (int*)ws;        ws += (size_t)(n + 1) * 4;
  int2* pairs = (int2*)ws;    ws += (size_t)E * 8;
  int* ssrc = (int*)ws;       ws += (size_t)E * 4;

  k_gemm<<<(n + 63) / 64, 256, 0, stream>>>(h, W, a, z, el, er, n);
  k_p1hist<<<b1, 256, 0, stream>>>(dst, gh, E, nbuck, b1);
  k_scanA<<<NB, 256, 0, stream>>>(gh, pbase, bsum, M);
  k_scanB<<<1, 256, 0, stream>>>(bsum, NB);
  k_scanC2<<<(M + 255) / 256, 256, 0, stream>>>(pbase, bsum, M);
  k_p1scat<<<b1, 256, 0, stream>>>(src, dst, pbase, pairs, E, nbuck, b1);
  k_p2<<<nbuck, 256, 0, stream>>>(pairs, pbase, ssrc, off, E, n, nbuck, b1);
  k_agg<<<(n + 15) / 16, 256, 0, stream>>>(off, ssrc, el, er, z, out, n);
}

// Round 6
// 298.881 us; speedup vs baseline: 6.5099x; 1.0976x over previous
//
#include <hip/hip_runtime.h>
#include <hip/hip_bf16.h>

#define IN_DIM 256
#define OUT_DIM 64
#define CHUNK 8192
#define BSH 9     // bucket = dst >> 9  (512 nodes per bucket)
#define P2CAP 12288

typedef short bf16x8 __attribute__((ext_vector_type(8)));
typedef float f32x4 __attribute__((ext_vector_type(4)));

__device__ inline unsigned short f2bf(float x) {
  unsigned int u = __float_as_uint(x);
  return (unsigned short)((u + 0x7FFFu + ((u >> 16) & 1u)) >> 16);
}

// ---- prep: W [256][64] fp32 -> Wbf in MFMA-fragment-major bf16 -------------
// frag f = (kc,ct,q,nq): Wbf[f*8 + j] = W[kc*32+q*8+j][ct*16+nq]
__global__ __launch_bounds__(256) void k_prep(const float* __restrict__ W,
                                              unsigned short* __restrict__ Wbf) {
  int f = blockIdx.x * 256 + threadIdx.x;  // 0..2047
  int kc = f >> 8, ct = (f >> 6) & 3, q = (f >> 4) & 3, nq = f & 15;
  int col = ct * 16 + nq, k0 = kc * 32 + q * 8;
  unsigned short v[8];
#pragma unroll
  for (int j = 0; j < 8; ++j) v[j] = f2bf(W[(size_t)(k0 + j) * OUT_DIM + col]);
  *(uint4*)(Wbf + (size_t)f * 8) = *(uint4*)v;
}

// ---- GEMM: z(bf16) = h @ W ; el = z@a1 ; er = z@a2 (MFMA, frag-major LDS) --
// 256 thr = 4 waves; 64 rows x 64 cols per block. A-fragments loaded straight
// from global per lane (no LDS); W fragments staged linearly (0 conflicts).
__global__ __launch_bounds__(256) void k_gemm(const float* __restrict__ h,
                                              const unsigned short* __restrict__ Wbf,
                                              const float* __restrict__ a,
                                              unsigned short* __restrict__ zb,
                                              float* __restrict__ el,
                                              float* __restrict__ er, int n) {
  __shared__ unsigned short Wb[16384];  // [kc][ct][lane][8] : 32 KB
  const int t = threadIdx.x;
  const int base = blockIdx.x * 64;

#pragma unroll
  for (int i = 0; i < 8; ++i) {
    int f = i * 256 + t;
    *(uint4*)&Wb[(size_t)f * 8] = *(const uint4*)&Wbf[(size_t)f * 8];
  }
  __syncthreads();

  const int w = t >> 6, lane = t & 63, nq = lane & 15, q = lane >> 4;
  const int row = base + w * 16 + nq;
  const bool rok = row < n;
  const float* hrow = h + (size_t)(rok ? row : 0) * IN_DIM + q * 8;

  f32x4 acc[4];
#pragma unroll
  for (int ct = 0; ct < 4; ++ct) acc[ct] = (f32x4){0.f, 0.f, 0.f, 0.f};

#pragma unroll
  for (int kc = 0; kc < 8; ++kc) {
    float4 v0 = make_float4(0.f, 0.f, 0.f, 0.f), v1 = v0;
    if (rok) {
      v0 = *(const float4*)(hrow + kc * 32);
      v1 = *(const float4*)(hrow + kc * 32 + 4);
    }
    unsigned short av[8] = {f2bf(v0.x), f2bf(v0.y), f2bf(v0.z), f2bf(v0.w),
                            f2bf(v1.x), f2bf(v1.y), f2bf(v1.z), f2bf(v1.w)};
    bf16x8 af = *(bf16x8*)av;
#pragma unroll
    for (int ct = 0; ct < 4; ++ct) {
      bf16x8 bfr = *(const bf16x8*)&Wb[((kc * 4 + ct) * 64 + lane) * 8];
      acc[ct] = __builtin_amdgcn_mfma_f32_16x16x32_bf16(af, bfr, acc[ct], 0, 0, 0);
    }
  }

  // epilogue. C/D: col = ct*16 + nq, row-in-tile = q*4 + r.
  float a1[4], a2[4];
#pragma unroll
  for (int ct = 0; ct < 4; ++ct) {
    a1[ct] = a[ct * 16 + nq];
    a2[ct] = a[OUT_DIM + ct * 16 + nq];
  }
#pragma unroll
  for (int r = 0; r < 4; ++r) {
    int orow = base + w * 16 + q * 4 + r;
    float p1 = 0.f, p2 = 0.f;
#pragma unroll
    for (int ct = 0; ct < 4; ++ct) {
      float v = acc[ct][r];
      p1 += v * a1[ct];
      p2 += v * a2[ct];
      if (orow < n) zb[(size_t)orow * OUT_DIM + ct * 16 + nq] = f2bf(v);
    }
    p1 += __shfl_xor(p1, 1); p1 += __shfl_xor(p1, 2);
    p1 += __shfl_xor(p1, 4); p1 += __shfl_xor(p1, 8);
    p2 += __shfl_xor(p2, 1); p2 += __shfl_xor(p2, 2);
    p2 += __shfl_xor(p2, 4); p2 += __shfl_xor(p2, 8);
    if (orow < n && nq == 0) { el[orow] = p1; er[orow] = p2; }
  }
}

// ------------- pass-1: per-block per-bucket histogram (bucket-major out) -----
__global__ __launch_bounds__(256) void k_p1hist(const int* __restrict__ dst,
                                                int* __restrict__ gh, int E,
                                                int nbuck, int b1) {
  __shared__ int hist[256];
  int t = threadIdx.x, b = blockIdx.x;
  hist[t] = 0;
  __syncthreads();
  int beg = b * CHUNK;
  for (int i = t; i < CHUNK; i += 256) {
    int e = beg + i;
    if (e < E) atomicAdd(&hist[dst[e] >> BSH], 1);
  }
  __syncthreads();
  if (t < nbuck) gh[t * b1 + b] = hist[t];
}

// ------------- generic scan: per-block (1024) exclusive + block totals -------
__global__ __launch_bounds__(256) void k_scanA(const int* __restrict__ in,
                                               int* __restrict__ out,
                                               int* __restrict__ bsum, int N) {
  __shared__ int wtot[4];
  int t = threadIdx.x, lane = t & 63, w = t >> 6;
  int idx = blockIdx.x * 1024 + t * 4;
  int d0 = idx + 0 < N ? in[idx + 0] : 0;
  int d1 = idx + 1 < N ? in[idx + 1] : 0;
  int d2 = idx + 2 < N ? in[idx + 2] : 0;
  int d3 = idx + 3 < N ? in[idx + 3] : 0;
  int tsum = d0 + d1 + d2 + d3;
  int incl = tsum;
  for (int o = 1; o < 64; o <<= 1) {
    int v = __shfl_up(incl, o);
    if (lane >= o) incl += v;
  }
  if (lane == 63) wtot[w] = incl;
  __syncthreads();
  int woff = 0;
  for (int i = 0; i < 4; ++i)
    if (i < w) woff += wtot[i];
  int btot = wtot[0] + wtot[1] + wtot[2] + wtot[3];
  int e = woff + incl - tsum;
  if (idx + 0 < N) out[idx + 0] = e; e += d0;
  if (idx + 1 < N) out[idx + 1] = e; e += d1;
  if (idx + 2 < N) out[idx + 2] = e; e += d2;
  if (idx + 3 < N) out[idx + 3] = e;
  if (t == 0) bsum[blockIdx.x] = btot;
}

__global__ __launch_bounds__(256) void k_scanB(int* __restrict__ bsum, int nb) {
  __shared__ int wtot[4];
  int t = threadIdx.x, lane = t & 63, w = t >> 6;
  int v = t < nb ? bsum[t] : 0;
  int incl = v;
  for (int o = 1; o < 64; o <<= 1) {
    int u = __shfl_up(incl, o);
    if (lane >= o) incl += u;
  }
  if (lane == 63) wtot[w] = incl;
  __syncthreads();
  int woff = 0;
  for (int i = 0; i < 4; ++i)
    if (i < w) woff += wtot[i];
  if (t < nb) bsum[t] = woff + incl - v;
}

__global__ __launch_bounds__(256) void k_scanC2(int* __restrict__ out,
                                                const int* __restrict__ bsum, int M) {
  int i = blockIdx.x * 256 + threadIdx.x;
  if (i < M) out[i] += bsum[i >> 10];
}

// ------------- pass-1 scatter: partition (dst,src) by bucket, dense runs -----
__global__ __launch_bounds__(256) void k_p1scat(const int* __restrict__ src,
                                                const int* __restrict__ dst,
                                                const int* __restrict__ pbase,
                                                int2* __restrict__ pairs, int E,
                                                int nbuck, int b1) {
  __shared__ int pb[256];
  __shared__ int cur[256];
  int t = threadIdx.x, b = blockIdx.x;
  if (t < nbuck) pb[t] = pbase[t * b1 + b];
  cur[t] = 0;
  __syncthreads();
  int beg = b * CHUNK;
  for (int i = t; i < CHUNK; i += 256) {
    int e = beg + i;
    if (e < E) {
      int d = dst[e], s = src[e];
      int bk = d >> BSH;
      int r = atomicAdd(&cur[bk], 1);
      pairs[pb[bk] + r] = make_int2(d, s);
    }
  }
}

// ------------- pass-2: per-bucket in-LDS counting sort + off[] emit ----------
__global__ __launch_bounds__(256) void k_p2(const int2* __restrict__ pairs,
                                            const int* __restrict__ pbase,
                                            int* __restrict__ ssrc,
                                            int* __restrict__ off, int E, int n,
                                            int nbuck, int b1) {
  __shared__ int deg[512];
  __shared__ int loff[512];
  __shared__ int cur[512];
  __shared__ int stage[P2CAP];
  __shared__ int wtot[4];
  int t = threadIdx.x, b = blockIdx.x;
  int beg = pbase[b * b1];
  int end = (b + 1 < nbuck) ? pbase[(b + 1) * b1] : E;
  int cnt = end - beg;
  int base = b << BSH;
  deg[t] = 0;
  deg[t + 256] = 0;
  __syncthreads();
  for (int i = t; i < cnt; i += 256) atomicAdd(&deg[pairs[beg + i].x - base], 1);
  __syncthreads();
  int a0 = deg[2 * t], a1 = deg[2 * t + 1];
  int ps = a0 + a1;
  int lane = t & 63, w = t >> 6;
  int inc = ps;
  for (int o = 1; o < 64; o <<= 1) {
    int v = __shfl_up(inc, o);
    if (lane >= o) inc += v;
  }
  if (lane == 63) wtot[w] = inc;
  __syncthreads();
  int woff = 0;
  for (int i = 0; i < 4; ++i)
    if (i < w) woff += wtot[i];
  int ex = woff + inc - ps;
  loff[2 * t] = ex;
  loff[2 * t + 1] = ex + a0;
  cur[2 * t] = ex;
  cur[2 * t + 1] = ex + a0;
  __syncthreads();
  for (int i = t; i < cnt; i += 256) {
    int2 p = pairs[beg + i];
    int r = atomicAdd(&cur[p.x - base], 1);
    if (r < P2CAP) stage[r] = p.y;
  }
  __syncthreads();
  for (int i = t; i < cnt; i += 256) ssrc[beg + i] = stage[i];
  for (int i = t; i < 512; i += 256) {
    int node = base + i;
    if (node <= n) off[node] = beg + loff[i];
  }
}

// ------- fused aggregate: softmax-sum + bf16 z gather + normalize + ELU ------
__global__ __launch_bounds__(256) void k_agg(const int* __restrict__ off,
                                             const int* __restrict__ ssrc,
                                             const float* __restrict__ el,
                                             const float* __restrict__ er,
                                             const unsigned short* __restrict__ zb,
                                             float* __restrict__ out, int N) {
  int t = threadIdx.x;
  int node = blockIdx.x * 16 + (t >> 4);
  if (node >= N) return;
  int c = (t & 15) * 4;
  int beg = off[node], end = off[node + 1];
  float erd = er[node];
  float ax = 0.f, ay = 0.f, az = 0.f, aw = 0.f, ssum = 0.f;
  for (int j = beg; j < end; ++j) {
    int s = ssrc[j];
    float x = el[s] + erd;
    x = x > 0.f ? x : 0.01f * x;
    float ex = __expf(x);
    ssum += ex;
    uint2 zv = *(const uint2*)(zb + (size_t)s * OUT_DIM + c);
    ax += ex * __uint_as_float(zv.x << 16);
    ay += ex * __uint_as_float(zv.x & 0xFFFF0000u);
    az += ex * __uint_as_float(zv.y << 16);
    aw += ex * __uint_as_float(zv.y & 0xFFFF0000u);
  }
  float4 o = make_float4(0.f, 0.f, 0.f, 0.f);
  if (end > beg) {
    float inv = 1.f / ssum;
    ax *= inv; ay *= inv; az *= inv; aw *= inv;
    o.x = ax > 0.f ? ax : __expf(ax) - 1.f;
    o.y = ay > 0.f ? ay : __expf(ay) - 1.f;
    o.z = az > 0.f ? az : __expf(az) - 1.f;
    o.w = aw > 0.f ? aw : __expf(aw) - 1.f;
  }
  *(float4*)(out + (size_t)node * OUT_DIM + c) = o;
}

extern "C" void kernel_launch(void* const* d_in, const int* in_sizes, int n_in,
                              void* d_out, int out_size, void* d_ws, size_t ws_size,
                              hipStream_t stream) {
  const float* h = (const float*)d_in[0];
  const float* W = (const float*)d_in[1];
  const float* a = (const float*)d_in[2];
  const int* src = (const int*)d_in[3];
  const int* dst = (const int*)d_in[4];
  const int n = in_sizes[0] / IN_DIM;  // 100000
  const int E = in_sizes[3];           // 1600000
  float* out = (float*)d_out;

  const int b1 = (E + CHUNK - 1) / CHUNK;         // 196
  const int nbuck = (n + (1 << BSH) - 1) >> BSH;  // 196
  const int M = nbuck * b1;                       // 38416
  const int NB = (M + 1023) / 1024;

  char* ws = (char*)d_ws;
  auto alloc = [&](size_t bytes) {
    char* p = ws;
    ws += (bytes + 15) & ~(size_t)15;
    return p;
  };
  unsigned short* Wbf = (unsigned short*)alloc(16384 * 2);
  unsigned short* zb = (unsigned short*)alloc((size_t)n * OUT_DIM * 2);
  float* el = (float*)alloc((size_t)n * 4);
  float* er = (float*)alloc((size_t)n * 4);
  int* gh = (int*)alloc((size_t)M * 4);
  int* pbase = (int*)alloc((size_t)M * 4);
  int* bsum = (int*)alloc(256 * 4);
  int* off = (int*)alloc((size_t)(n + 1) * 4);
  int2* pairs = (int2*)alloc((size_t)E * 8);
  int* ssrc = (int*)alloc((size_t)E * 4);

  k_prep<<<8, 256, 0, stream>>>(W, Wbf);
  k_gemm<<<(n + 63) / 64, 256, 0, stream>>>(h, Wbf, a, zb, el, er, n);
  k_p1hist<<<b1, 256, 0, stream>>>(dst, gh, E, nbuck, b1);
  k_scanA<<<NB, 256, 0, stream>>>(gh, pbase, bsum, M);
  k_scanB<<<1, 256, 0, stream>>>(bsum, NB);
  k_scanC2<<<(M + 255) / 256, 256, 0, stream>>>(pbase, bsum, M);
  k_p1scat<<<b1, 256, 0, stream>>>(src, dst, pbase, pairs, E, nbuck, b1);
  k_p2<<<nbuck, 256, 0, stream>>>(pairs, pbase, ssrc, off, E, n, nbuck, b1);
  k_agg<<<(n + 15) / 16, 256, 0, stream>>>(off, ssrc, el, er, zb, out, n);
}

// Round 7
// 275.451 us; speedup vs baseline: 7.0636x; 1.0851x over previous
//
#include <hip/hip_runtime.h>
#include <hip/hip_bf16.h>

#define IN_DIM 256
#define OUT_DIM 64
#define CHUNK 4096
#define BSH 8      // bucket = dst >> 8 (256 nodes/bucket)
#define P2CAP 6144

typedef short bf16x8 __attribute__((ext_vector_type(8)));
typedef float f32x4 __attribute__((ext_vector_type(4)));

__device__ inline unsigned short f2bf(float x) {
  unsigned int u = __float_as_uint(x);
  return (unsigned short)((u + 0x7FFFu + ((u >> 16) & 1u)) >> 16);
}

// ---- prep: W [256][64] fp32 -> Wbf in MFMA-fragment-major bf16 -------------
// frag f = (kc,ct,lane): Wbf[f*8 + j] = W[kc*32+(lane>>4)*8+j][ct*16+(lane&15)]
__global__ __launch_bounds__(256) void k_prep(const float* __restrict__ W,
                                              unsigned short* __restrict__ Wbf) {
  int f = blockIdx.x * 256 + threadIdx.x;  // 0..2047
  int kc = f >> 8, ct = (f >> 6) & 3, q = (f >> 4) & 3, nq = f & 15;
  int col = ct * 16 + nq, k0 = kc * 32 + q * 8;
  unsigned short v[8];
#pragma unroll
  for (int j = 0; j < 8; ++j) v[j] = f2bf(W[(size_t)(k0 + j) * OUT_DIM + col]);
  *(uint4*)(Wbf + (size_t)f * 8) = *(uint4*)v;
}

// ---- GEMM: zb(bf16) = h @ W ; el = z@a1 ; er = z@a2 -------------------------
// 256 thr = 4 waves, 64 rows/block. A staged in LDS via coalesced float4 reads;
// W fragments read directly from frag-major global (L2-hot 32 KB).
__global__ __launch_bounds__(256) void k_gemm(const float* __restrict__ h,
                                              const unsigned short* __restrict__ Wbf,
                                              const float* __restrict__ a,
                                              unsigned short* __restrict__ zb,
                                              float* __restrict__ el,
                                              float* __restrict__ er, int n) {
  __shared__ unsigned short Ab[64][264];  // 33 KB; +8 pad keeps writes 2-way max
  const int t = threadIdx.x;
  const int base = blockIdx.x * 64;

  // stage h tile: 64 rows x 256 cols, 4096 float4, 16/thread, lane-contiguous.
#pragma unroll
  for (int i = 0; i < 16; ++i) {
    int f = i * 256 + t;
    int r = f >> 6, c4 = f & 63;
    int row = base + r;
    float4 v = make_float4(0.f, 0.f, 0.f, 0.f);
    if (row < n) v = *(const float4*)(h + (size_t)row * IN_DIM + c4 * 4);
    unsigned int p0 = (unsigned int)f2bf(v.x) | ((unsigned int)f2bf(v.y) << 16);
    unsigned int p1 = (unsigned int)f2bf(v.z) | ((unsigned int)f2bf(v.w) << 16);
    *(uint2*)&Ab[r][c4 * 4] = make_uint2(p0, p1);
  }
  __syncthreads();

  const int w = t >> 6, lane = t & 63, nq = lane & 15, q = lane >> 4;

  f32x4 acc[4];
#pragma unroll
  for (int ct = 0; ct < 4; ++ct) acc[ct] = (f32x4){0.f, 0.f, 0.f, 0.f};

#pragma unroll
  for (int kc = 0; kc < 8; ++kc) {
    bf16x8 af = *(const bf16x8*)&Ab[w * 16 + nq][kc * 32 + q * 8];
#pragma unroll
    for (int ct = 0; ct < 4; ++ct) {
      bf16x8 bfr = *(const bf16x8*)(Wbf + (size_t)((kc * 4 + ct) * 64 + lane) * 8);
      acc[ct] = __builtin_amdgcn_mfma_f32_16x16x32_bf16(af, bfr, acc[ct], 0, 0, 0);
    }
  }

  // epilogue. C/D: col = ct*16 + nq, row-in-tile = q*4 + r.
  float a1[4], a2[4];
#pragma unroll
  for (int ct = 0; ct < 4; ++ct) {
    a1[ct] = a[ct * 16 + nq];
    a2[ct] = a[OUT_DIM + ct * 16 + nq];
  }
#pragma unroll
  for (int r = 0; r < 4; ++r) {
    int orow = base + w * 16 + q * 4 + r;
    float p1 = 0.f, p2 = 0.f;
#pragma unroll
    for (int ct = 0; ct < 4; ++ct) {
      float v = acc[ct][r];
      p1 += v * a1[ct];
      p2 += v * a2[ct];
      if (orow < n) zb[(size_t)orow * OUT_DIM + ct * 16 + nq] = f2bf(v);
    }
    p1 += __shfl_xor(p1, 1); p1 += __shfl_xor(p1, 2);
    p1 += __shfl_xor(p1, 4); p1 += __shfl_xor(p1, 8);
    p2 += __shfl_xor(p2, 1); p2 += __shfl_xor(p2, 2);
    p2 += __shfl_xor(p2, 4); p2 += __shfl_xor(p2, 8);
    if (orow < n && nq == 0) { el[orow] = p1; er[orow] = p2; }
  }
}

// ------------- pass-1: per-block per-bucket histogram (bucket-major out) -----
__global__ __launch_bounds__(256) void k_p1hist(const int* __restrict__ dst,
                                                int* __restrict__ gh, int E,
                                                int nbuck, int b1) {
  __shared__ int hist[512];
  int t = threadIdx.x, b = blockIdx.x;
  hist[t] = 0;
  hist[t + 256] = 0;
  __syncthreads();
  int beg = b * CHUNK;
#pragma unroll
  for (int i = t; i < CHUNK; i += 256) {
    int e = beg + i;
    if (e < E) atomicAdd(&hist[dst[e] >> BSH], 1);
  }
  __syncthreads();
  for (int i = t; i < nbuck; i += 256) gh[i * b1 + b] = hist[i];
}

// ------------- generic scan: per-block (1024) exclusive + block totals -------
__global__ __launch_bounds__(256) void k_scanA(const int* __restrict__ in,
                                               int* __restrict__ out,
                                               int* __restrict__ bsum, int N) {
  __shared__ int wtot[4];
  int t = threadIdx.x, lane = t & 63, w = t >> 6;
  int idx = blockIdx.x * 1024 + t * 4;
  int d0 = idx + 0 < N ? in[idx + 0] : 0;
  int d1 = idx + 1 < N ? in[idx + 1] : 0;
  int d2 = idx + 2 < N ? in[idx + 2] : 0;
  int d3 = idx + 3 < N ? in[idx + 3] : 0;
  int tsum = d0 + d1 + d2 + d3;
  int incl = tsum;
  for (int o = 1; o < 64; o <<= 1) {
    int v = __shfl_up(incl, o);
    if (lane >= o) incl += v;
  }
  if (lane == 63) wtot[w] = incl;
  __syncthreads();
  int woff = 0;
  for (int i = 0; i < 4; ++i)
    if (i < w) woff += wtot[i];
  int btot = wtot[0] + wtot[1] + wtot[2] + wtot[3];
  int e = woff + incl - tsum;
  if (idx + 0 < N) out[idx + 0] = e; e += d0;
  if (idx + 1 < N) out[idx + 1] = e; e += d1;
  if (idx + 2 < N) out[idx + 2] = e; e += d2;
  if (idx + 3 < N) out[idx + 3] = e;
  if (t == 0) bsum[blockIdx.x] = btot;
}

__global__ __launch_bounds__(256) void k_scanB(int* __restrict__ bsum, int nb) {
  __shared__ int wtot[4];
  int t = threadIdx.x, lane = t & 63, w = t >> 6;
  int v = t < nb ? bsum[t] : 0;
  int incl = v;
  for (int o = 1; o < 64; o <<= 1) {
    int u = __shfl_up(incl, o);
    if (lane >= o) incl += u;
  }
  if (lane == 63) wtot[w] = incl;
  __syncthreads();
  int woff = 0;
  for (int i = 0; i < 4; ++i)
    if (i < w) woff += wtot[i];
  if (t < nb) bsum[t] = woff + incl - v;
}

__global__ __launch_bounds__(256) void k_scanC2(int* __restrict__ out,
                                                const int* __restrict__ bsum, int M) {
  int i = blockIdx.x * 256 + threadIdx.x;
  if (i < M) out[i] += bsum[i >> 10];
}

// ------------- pass-1 scatter: partition (dst,src) by bucket -----------------
__global__ __launch_bounds__(256) void k_p1scat(const int* __restrict__ src,
                                                const int* __restrict__ dst,
                                                const int* __restrict__ pbase,
                                                int2* __restrict__ pairs, int E,
                                                int nbuck, int b1) {
  __shared__ int pb[512];
  __shared__ int cur[512];
  int t = threadIdx.x, b = blockIdx.x;
  for (int i = t; i < 512; i += 256) {
    pb[i] = (i < nbuck) ? pbase[i * b1 + b] : 0;
    cur[i] = 0;
  }
  __syncthreads();
  int beg = b * CHUNK;
#pragma unroll
  for (int i = t; i < CHUNK; i += 256) {
    int e = beg + i;
    if (e < E) {
      int d = dst[e], s = src[e];
      int bk = d >> BSH;
      int r = atomicAdd(&cur[bk], 1);
      pairs[pb[bk] + r] = make_int2(d, s);
    }
  }
}

// ------------- pass-2: per-bucket in-LDS counting sort + off[] emit ----------
__global__ __launch_bounds__(256) void k_p2(const int2* __restrict__ pairs,
                                            const int* __restrict__ pbase,
                                            int* __restrict__ ssrc,
                                            int* __restrict__ off, int E, int n,
                                            int nbuck, int b1) {
  __shared__ int deg[256];
  __shared__ int loff[256];
  __shared__ int cur[256];
  __shared__ int stage[P2CAP];
  __shared__ int wtot[4];
  int t = threadIdx.x, b = blockIdx.x;
  int beg = pbase[b * b1];
  int end = (b + 1 < nbuck) ? pbase[(b + 1) * b1] : E;
  int cnt = end - beg;
  int base = b << BSH;
  deg[t] = 0;
  __syncthreads();
  for (int i = t; i < cnt; i += 256) atomicAdd(&deg[pairs[beg + i].x - base], 1);
  __syncthreads();
  int v = deg[t];
  int lane = t & 63, w = t >> 6;
  int inc = v;
  for (int o = 1; o < 64; o <<= 1) {
    int u = __shfl_up(inc, o);
    if (lane >= o) inc += u;
  }
  if (lane == 63) wtot[w] = inc;
  __syncthreads();
  int woff = 0;
  for (int i = 0; i < 4; ++i)
    if (i < w) woff += wtot[i];
  int ex = woff + inc - v;
  loff[t] = ex;
  cur[t] = ex;
  __syncthreads();
  for (int i = t; i < cnt; i += 256) {
    int2 p = pairs[beg + i];
    int r = atomicAdd(&cur[p.x - base], 1);
    if (r < P2CAP) stage[r] = p.y;
  }
  __syncthreads();
  for (int i = t; i < cnt; i += 256) ssrc[beg + i] = stage[i];
  int node = base + t;
  if (node <= n) off[node] = beg + loff[t];
}

// ------- fused aggregate: x4-unrolled gather for MLP --------------------------
__global__ __launch_bounds__(256) void k_agg(const int* __restrict__ off,
                                             const int* __restrict__ ssrc,
                                             const float* __restrict__ el,
                                             const float* __restrict__ er,
                                             const unsigned short* __restrict__ zb,
                                             float* __restrict__ out, int N) {
  int t = threadIdx.x;
  int node = blockIdx.x * 16 + (t >> 4);
  if (node >= N) return;
  int cq = (t & 15) * 4;
  int beg = off[node], end = off[node + 1];
  float erd = er[node];
  float ax = 0.f, ay = 0.f, az = 0.f, aw = 0.f, ssum = 0.f;
  int j = beg;
  for (; j + 4 <= end; j += 4) {
    int s0 = ssrc[j], s1 = ssrc[j + 1], s2 = ssrc[j + 2], s3 = ssrc[j + 3];
    uint2 z0 = *(const uint2*)(zb + (s0 << 6) + cq);
    uint2 z1 = *(const uint2*)(zb + (s1 << 6) + cq);
    uint2 z2 = *(const uint2*)(zb + (s2 << 6) + cq);
    uint2 z3 = *(const uint2*)(zb + (s3 << 6) + cq);
    float x0 = el[s0] + erd, x1 = el[s1] + erd;
    float x2 = el[s2] + erd, x3 = el[s3] + erd;
    x0 = x0 > 0.f ? x0 : 0.01f * x0;
    x1 = x1 > 0.f ? x1 : 0.01f * x1;
    x2 = x2 > 0.f ? x2 : 0.01f * x2;
    x3 = x3 > 0.f ? x3 : 0.01f * x3;
    float e0 = __expf(x0), e1 = __expf(x1), e2 = __expf(x2), e3 = __expf(x3);
    ssum += (e0 + e1) + (e2 + e3);
    ax += e0 * __uint_as_float(z0.x << 16) + e1 * __uint_as_float(z1.x << 16) +
          e2 * __uint_as_float(z2.x << 16) + e3 * __uint_as_float(z3.x << 16);
    ay += e0 * __uint_as_float(z0.x & 0xFFFF0000u) + e1 * __uint_as_float(z1.x & 0xFFFF0000u) +
          e2 * __uint_as_float(z2.x & 0xFFFF0000u) + e3 * __uint_as_float(z3.x & 0xFFFF0000u);
    az += e0 * __uint_as_float(z0.y << 16) + e1 * __uint_as_float(z1.y << 16) +
          e2 * __uint_as_float(z2.y << 16) + e3 * __uint_as_float(z3.y << 16);
    aw += e0 * __uint_as_float(z0.y & 0xFFFF0000u) + e1 * __uint_as_float(z1.y & 0xFFFF0000u) +
          e2 * __uint_as_float(z2.y & 0xFFFF0000u) + e3 * __uint_as_float(z3.y & 0xFFFF0000u);
  }
  for (; j < end; ++j) {
    int s = ssrc[j];
    uint2 zv = *(const uint2*)(zb + (s << 6) + cq);
    float x = el[s] + erd;
    x = x > 0.f ? x : 0.01f * x;
    float ex = __expf(x);
    ssum += ex;
    ax += ex * __uint_as_float(zv.x << 16);
    ay += ex * __uint_as_float(zv.x & 0xFFFF0000u);
    az += ex * __uint_as_float(zv.y << 16);
    aw += ex * __uint_as_float(zv.y & 0xFFFF0000u);
  }
  float4 o = make_float4(0.f, 0.f, 0.f, 0.f);
  if (end > beg) {
    float inv = 1.f / ssum;
    ax *= inv; ay *= inv; az *= inv; aw *= inv;
    o.x = ax > 0.f ? ax : __expf(ax) - 1.f;
    o.y = ay > 0.f ? ay : __expf(ay) - 1.f;
    o.z = az > 0.f ? az : __expf(az) - 1.f;
    o.w = aw > 0.f ? aw : __expf(aw) - 1.f;
  }
  *(float4*)(out + ((size_t)node << 6) + cq) = o;
}

extern "C" void kernel_launch(void* const* d_in, const int* in_sizes, int n_in,
                              void* d_out, int out_size, void* d_ws, size_t ws_size,
                              hipStream_t stream) {
  const float* h = (const float*)d_in[0];
  const float* W = (const float*)d_in[1];
  const float* a = (const float*)d_in[2];
  const int* src = (const int*)d_in[3];
  const int* dst = (const int*)d_in[4];
  const int n = in_sizes[0] / IN_DIM;  // 100000
  const int E = in_sizes[3];           // 1600000
  float* out = (float*)d_out;

  const int b1 = (E + CHUNK - 1) / CHUNK;         // 391
  const int nbuck = (n + (1 << BSH) - 1) >> BSH;  // 391
  const int M = nbuck * b1;                       // 152881
  const int NB = (M + 1023) / 1024;               // 150

  char* ws = (char*)d_ws;
  auto alloc = [&](size_t bytes) {
    char* p = ws;
    ws += (bytes + 15) & ~(size_t)15;
    return p;
  };
  unsigned short* Wbf = (unsigned short*)alloc(16384 * 2);
  unsigned short* zb = (unsigned short*)alloc((size_t)n * OUT_DIM * 2);
  float* el = (float*)alloc((size_t)n * 4);
  float* er = (float*)alloc((size_t)n * 4);
  int* gh = (int*)alloc((size_t)M * 4);
  int* pbase = (int*)alloc((size_t)M * 4);
  int* bsum = (int*)alloc(256 * 4);
  int* off = (int*)alloc((size_t)(n + 1) * 4);
  int2* pairs = (int2*)alloc((size_t)E * 8);
  int* ssrc = (int*)alloc((size_t)E * 4);

  k_prep<<<8, 256, 0, stream>>>(W, Wbf);
  k_gemm<<<(n + 63) / 64, 256, 0, stream>>>(h, Wbf, a, zb, el, er, n);
  k_p1hist<<<b1, 256, 0, stream>>>(dst, gh, E, nbuck, b1);
  k_scanA<<<NB, 256, 0, stream>>>(gh, pbase, bsum, M);
  k_scanB<<<1, 256, 0, stream>>>(bsum, NB);
  k_scanC2<<<(M + 255) / 256, 256, 0, stream>>>(pbase, bsum, M);
  k_p1scat<<<b1, 256, 0, stream>>>(src, dst, pbase, pairs, E, nbuck, b1);
  k_p2<<<nbuck, 256, 0, stream>>>(pairs, pbase, ssrc, off, E, n, nbuck, b1);
  k_agg<<<(n + 15) / 16, 256, 0, stream>>>(off, ssrc, el, er, zb, out, n);
}